// Round 15
// baseline (115.573 us; speedup 1.0000x reference)
//
#include <hip/hip_runtime.h>
#include <hip/hip_bf16.h>
#include <math.h>

#define IN_F 512
#define OUT_F 256
#define ALPHA 0.2f
#define CAP 512     // max row degree; deg ~ Poisson(32)
#define NCHAIN 16   // sub-chains per row for parallel linked-list traversal

typedef __attribute__((ext_vector_type(8))) short bf16x8;
typedef __attribute__((ext_vector_type(4))) float f32x4;

// pack two f32 -> one u32 of 2 bf16 (round-to-nearest, ties up): 5 VALU ops
static __device__ __forceinline__ unsigned int pk2(float a, float b) {
  unsigned int ua = __builtin_bit_cast(unsigned int, a) + 0x8000u;
  unsigned int ub = __builtin_bit_cast(unsigned int, b) + 0x8000u;
  return (ua >> 16) | (ub & 0xffff0000u);
}
static __device__ __forceinline__ bf16x8 pack8(float4 lo, float4 hi) {
  union { unsigned int u[4]; bf16x8 v; } r;
  r.u[0] = pk2(lo.x, lo.y); r.u[1] = pk2(lo.z, lo.w);
  r.u[2] = pk2(hi.x, hi.y); r.u[3] = pk2(hi.z, hi.w);
  return r.v;
}
static __device__ __forceinline__ unsigned short f2bf(float f) {
  unsigned int u = __builtin_bit_cast(unsigned int, f);
  return (unsigned short)((u + 0x8000u) >> 16);
}
static __device__ __forceinline__ float bf_lo(unsigned int u) {
  return __builtin_bit_cast(float, u << 16);
}
static __device__ __forceinline__ float bf_hi(unsigned int u) {
  return __builtin_bit_cast(float, u & 0xffff0000u);
}

// ================= mega: [0,gblocks) = 32x64 GEMM tiles (NO LDS staging), rest = edge fill =================
// Round-14 lesson: the stage->barrier->MFMA structure cost ~33us at this shape (only 4
// K-iters -> vmcnt(0)+barrier drain dominates). Here each lane loads its MFMA fragments
// DIRECTLY from global (8 contiguous f32 = 2 float4), converts in-reg, MFMAs. No K-loop
// barriers, no big LDS; A reuse across the 4 waves is served by L1 (16KB tile < 32KB L1).
__global__ __launch_bounds__(256) void mega(const float* __restrict__ x,
                                            const float* __restrict__ W,
                                            const float* __restrict__ bias,
                                            const float* __restrict__ a,
                                            const int* __restrict__ edges,
                                            unsigned short* __restrict__ hb,
                                            float* __restrict__ s1p,
                                            float* __restrict__ s2p,
                                            float* __restrict__ hsump,
                                            int* __restrict__ head,
                                            int2* __restrict__ rec,
                                            int N_, int E_, int m32, int gblocks) {
  const int tid = threadIdx.x;
  const int vb = blockIdx.x;

  if (vb >= gblocks) {
    // ---- edge fill: 16-way per-row linked lists. Heads are negative on entry (0xAA
    // poison call 1; rowk leaves -1). rowk's reset is REQUIRED (round-13 tripwire).
    int idx = (vb - gblocks) * 256 + tid;
    if (idx < E_) {
      int srcv = edges[idx];
      int tgtv = edges[E_ + idx];
      int old = atomicExch(&head[srcv * NCHAIN + (idx & (NCHAIN - 1))], idx);
      rec[idx] = make_int2(old, tgtv);
    }
    return;
  }

  __shared__ float s1t[32], s2t[32], ht[64];

  const int mt = vb % m32;
  const int bn4 = vb / m32;              // 0..3
  const int bm = mt * 32;
  const int bn = bn4 * 64;
  const int wave = tid >> 6, lane = tid & 63;
  const int lr = lane & 15, lk = lane >> 4;

  // fragment source rows (clamped; out-of-range lanes' results discarded at store)
  int gr0 = bm + lr;        if (gr0 >= N_) gr0 = N_ - 1;
  int gr1 = bm + 16 + lr;   if (gr1 >= N_) gr1 = N_ - 1;
  const float* xr0 = x + (size_t)gr0 * IN_F;
  const float* xr1 = x + (size_t)gr1 * IN_F;
  const float* wr  = W + (size_t)(bn + wave * 16 + lr) * IN_F;   // < 256 always

  f32x4 acc[2] = {};   // fm in {0,1}: rows bm + fm*16 + lk*4 + i, col bn + wave*16 + lr

#pragma unroll 4
  for (int kk = 0; kk < IN_F; kk += 32) {
    const int kb = kk + lk * 8;
    float4 a0 = *(const float4*)&xr0[kb];
    float4 a1 = *(const float4*)&xr0[kb + 4];
    float4 c0 = *(const float4*)&xr1[kb];
    float4 c1 = *(const float4*)&xr1[kb + 4];
    float4 b0 = *(const float4*)&wr[kb];
    float4 b1 = *(const float4*)&wr[kb + 4];
    bf16x8 fb = pack8(b0, b1);
    acc[0] = __builtin_amdgcn_mfma_f32_16x16x32_bf16(pack8(a0, a1), fb, acc[0], 0, 0, 0);
    acc[1] = __builtin_amdgcn_mfma_f32_16x16x32_bf16(pack8(c0, c1), fb, acc[1], 0, 0, 0);
  }

  // ---- epilogue. C/D layout: col=lane&15, row=(lane>>4)*4+reg ----
  if (tid < 32) { s1t[tid] = 0.f; s2t[tid] = 0.f; }
  __syncthreads();

  const int gcv = bn + wave * 16 + lr;
  const float av = a[gcv], bv2 = a[OUT_F + gcv], biasv = bias[gcv];
  float csum = 0.f;
#pragma unroll
  for (int fm = 0; fm < 2; ++fm) {
#pragma unroll
    for (int i = 0; i < 4; ++i) {
      int lrow = fm * 16 + lk * 4 + i;
      int gr = bm + lrow;
      bool valid = (gr < N_);
      float v = valid ? acc[fm][i] + biasv : 0.f;
      if (valid) hb[(size_t)gr * OUT_F + gcv] = f2bf(v);
      csum += v;
      // partial dot over this wave's 16 cols; combine across the lr group
      float p1 = v * av;
      float p2 = v * bv2;
#pragma unroll
      for (int off = 1; off < 16; off <<= 1) {
        p1 += __shfl_xor(p1, off);
        p2 += __shfl_xor(p2, off);
      }
      if (lr == 0 && valid) {      // 4 waves contribute per row -> LDS combine
        atomicAdd(&s1t[lrow], p1);
        atomicAdd(&s2t[lrow], p2);
      }
    }
  }
  // column sums: rows live across the lk group (xor 16,32); one writer per col
#pragma unroll
  for (int off = 16; off < 64; off <<= 1) csum += __shfl_xor(csum, off);
  if (lk == 0) ht[wave * 16 + lr] = csum;
  __syncthreads();

  if (tid < 32) {
    int gr = bm + tid;
    if (gr < N_) {
      s1p[(size_t)gr * 4 + bn4] = s1t[tid];
      s2p[(size_t)gr * 4 + bn4] = s2t[tid];
    }
  }
  if (tid < 64) hsump[(size_t)mt * OUT_F + bn + tid] = ht[tid];
}

// ================= rowk: 1 row / 128-thread block; uint4 (16B) gather =================
__global__ __launch_bounds__(128) void rowk(const unsigned short* __restrict__ hb,
                                            const float* __restrict__ s1p,
                                            const float* __restrict__ s2p,
                                            const float* __restrict__ hsump,
                                            int* __restrict__ head,
                                            const int2* __restrict__ rec,
                                            float* __restrict__ out,
                                            int N_, int E_, int m32) {
  __shared__ int s_tgt[CAP];
  __shared__ float s_w[CAP];
  __shared__ float s_acc[4][OUT_F];   // per-group gather partials
  __shared__ float s_red[4];
  __shared__ int s_cnt;

  const int t = threadIdx.x;          // 0..127
  const int lane = t & 63, wv = t >> 6;
  const int row = blockIdx.x;
  const float invN = 1.0f / (float)N_;

  if (t == 0) s_cnt = 0;
  __syncthreads();

  // single-pass chain walk: grab slots via LDS cursor (slot order only permutes
  // FP summation order -> ~1ulp wobble, far under threshold)
  if (t < NCHAIN) {
    int e = head[row * NCHAIN + t];
    int guard = 0;
    while (e >= 0 && e < E_ && guard < CAP) {
      int2 rr = rec[e];
      int slot = atomicAdd(&s_cnt, 1);
      if (slot < CAP) s_tgt[slot] = rr.y;
      ++guard;
      e = rr.x;
    }
    // REQUIRED leave-clean reset (round-13 tripwire): next call's edge fill must
    // see negative heads, else stale indices get linked into new chains as cycles.
    head[row * NCHAIN + t] = -1;
  }
  __syncthreads();
  int deg = s_cnt;
  if (deg > CAP) deg = CAP;

  // raw leaky scores; s1/s2 = sum of 4 per-n-block partials (one float4 each)
  float4 sv = *(const float4*)&s1p[(size_t)row * 4];
  float s1i = (sv.x + sv.y) + (sv.z + sv.w);
  for (int q = t; q < deg; q += 128) {
    int tg = s_tgt[q];
    float4 s2v = *(const float4*)&s2p[(size_t)tg * 4];
    float s = s1i + ((s2v.x + s2v.y) + (s2v.z + s2v.w));
    s_w[q] = (s > 0.f) ? s : ALPHA * s;
  }
  __syncthreads();

  // duplicate merge: leader slot gets cnt*score, others -inf (own-slot writes only)
  for (int q = t; q < deg; q += 128) {
    int tg = s_tgt[q];
    int first = q, cnt = 0;
    for (int j = 0; j < deg; ++j) {
      int tj = s_tgt[j];
      cnt += (tj == tg);
      if (tj == tg && j < first) first = j;
    }
    float v;
    if (first == q) {
      v = (float)cnt * s_w[q];
      if (v == 0.f) v = -INFINITY;  // adj==0 -> NEG_BIG -> excluded
    } else {
      v = -INFINITY;
    }
    s_w[q] = v;
  }

  // block max (2 waves)
  float m = -INFINITY;
  for (int q = t; q < deg; q += 128) m = fmaxf(m, s_w[q]);
#pragma unroll
  for (int off = 32; off; off >>= 1) m = fmaxf(m, __shfl_xor(m, off));
  if (lane == 0) s_red[wv] = m;
  __syncthreads();
  m = fmaxf(s_red[0], s_red[1]);

  bool uniform = (deg == 0) || (m == -INFINITY);

  // exp + denom (skipped when uniform -> avoids -inf - -inf NaN)
  float dsum = 0.f;
  if (!uniform) {
    for (int q = t; q < deg; q += 128) {
      float e = __expf(s_w[q] - m);
      s_w[q] = e;
      dsum += e;
    }
  }
#pragma unroll
  for (int off = 32; off; off >>= 1) dsum += __shfl_xor(dsum, off);
  if (lane == 0) s_red[2 + wv] = dsum;
  __syncthreads();
  float inv = 1.0f / (s_red[2] + s_red[3]);

  float2* out2 = (float2*)(out + (size_t)row * OUT_F);
  if (uniform) {
    // empty row -> softmax of constant row -> mean of h (on-demand column sum)
    float A = 0.f, B = 0.f;
    for (int mt = 0; mt < m32; ++mt) {
      A += hsump[(size_t)mt * OUT_F + 2 * t];
      B += hsump[(size_t)mt * OUT_F + 2 * t + 1];
    }
    out2[t] = make_float2(A * invN, B * invN);
    return;
  }

  // ---- gather: 4 groups x 32 lanes; group g handles edges q ≡ g (mod 4).
  // Each lane loads uint4 = 8 bf16 features at lane32*8 (16B, coalesced 512B/edge).
  const int g = t >> 5, lane32 = t & 31;
  float a0 = 0.f, a1 = 0.f, a2 = 0.f, a3 = 0.f, a4 = 0.f, a5 = 0.f, a6 = 0.f, a7 = 0.f;
  const uint4* hb4 = (const uint4*)hb;   // 8 bf16 per uint4; row stride = 32 uint4
#pragma unroll 2
  for (int q = g; q < deg; q += 4) {
    float w = s_w[q];
    uint4 u = hb4[(size_t)s_tgt[q] * 32 + lane32];
    a0 += w * bf_lo(u.x); a1 += w * bf_hi(u.x);
    a2 += w * bf_lo(u.y); a3 += w * bf_hi(u.y);
    a4 += w * bf_lo(u.z); a5 += w * bf_hi(u.z);
    a6 += w * bf_lo(u.w); a7 += w * bf_hi(u.w);
  }
  {
    float* dst = &s_acc[g][lane32 * 8];
    dst[0] = a0; dst[1] = a1; dst[2] = a2; dst[3] = a3;
    dst[4] = a4; dst[5] = a5; dst[6] = a6; dst[7] = a7;
  }
  __syncthreads();
  // combine the 4 group-partials; thread t owns features 2t, 2t+1
  float A = ((s_acc[0][2 * t] + s_acc[1][2 * t]) + (s_acc[2][2 * t] + s_acc[3][2 * t]));
  float B = ((s_acc[0][2 * t + 1] + s_acc[1][2 * t + 1]) +
             (s_acc[2][2 * t + 1] + s_acc[3][2 * t + 1]));
  out2[t] = make_float2(A * inv, B * inv);
}

extern "C" void kernel_launch(void* const* d_in, const int* in_sizes, int n_in,
                              void* d_out, int out_size, void* d_ws, size_t ws_size,
                              hipStream_t stream) {
  const float* x = (const float*)d_in[0];
  const float* W = (const float*)d_in[1];
  const float* b = (const float*)d_in[2];
  const float* a = (const float*)d_in[3];
  const int* edges = (const int*)d_in[4];
  float* out = (float*)d_out;

  int N_ = in_sizes[0] / IN_F;   // 10000
  int E_ = in_sizes[4] / 2;      // 320000

  char* ws = (char*)d_ws;
  size_t off = 0;
  auto alloc = [&](size_t bytes) {
    char* q = ws + off;
    off = (off + bytes + 255) & ~(size_t)255;
    return q;
  };
  int m32 = (N_ + 31) / 32;
  unsigned short* hb    = (unsigned short*)alloc((size_t)N_ * OUT_F * sizeof(unsigned short));
  float*          s1p   = (float*)alloc((size_t)N_ * 4 * sizeof(float));
  float*          s2p   = (float*)alloc((size_t)N_ * 4 * sizeof(float));
  float*          hsump = (float*)alloc((size_t)m32 * OUT_F * sizeof(float));
  int*            head  = (int*)alloc((size_t)NCHAIN * N_ * sizeof(int));
  int2*           rec   = (int2*)alloc((size_t)E_ * sizeof(int2));

  int gblocks = m32 * 4;                 // 32x64 tiles covering 256 cols
  int fblocks = (E_ + 255) / 256;

  mega<<<gblocks + fblocks, 256, 0, stream>>>(x, W, b, a, edges, hb, s1p, s2p, hsump,
                                              head, rec, N_, E_, m32, gblocks);
  rowk<<<N_, 128, 0, stream>>>(hb, s1p, s2p, hsump, head, rec, out, N_, E_, m32);
}

// Round 16
// 69.792 us; speedup vs baseline: 1.6560x; 1.6560x over previous
//
#include <hip/hip_runtime.h>
#include <hip/hip_bf16.h>
#include <math.h>

#define IN_F 512
#define OUT_F 256
#define ALPHA 0.2f
#define CAP 512     // max row degree; deg ~ Poisson(32)
#define NCHAIN 16   // sub-chains per row for parallel linked-list traversal

typedef __attribute__((ext_vector_type(8))) short bf16x8;
typedef __attribute__((ext_vector_type(4))) float f32x4;

// round-to-nearest (ties up): 2 VALU ops
static __device__ __forceinline__ unsigned short f2bf(float f) {
  unsigned int u = __builtin_bit_cast(unsigned int, f);
  return (unsigned short)((u + 0x8000u) >> 16);
}
static __device__ __forceinline__ float bf_lo(unsigned int u) {
  return __builtin_bit_cast(float, u << 16);
}
static __device__ __forceinline__ float bf_hi(unsigned int u) {
  return __builtin_bit_cast(float, u & 0xffff0000u);
}

// ================= fillk: edge fill, 16-way per-row linked lists =================
// Separate dispatch (round-15 split) so its scattered atomics get their own profile row
// and don't share CUs with GEMM staging. Heads are negative on entry (0xAA poison on
// call 1; rowk leaves -1 every call — REQUIRED, round-13 tripwire).
__global__ __launch_bounds__(256) void fillk(const int* __restrict__ edges,
                                             int* __restrict__ head,
                                             int2* __restrict__ rec, int E_) {
  int idx = blockIdx.x * 256 + threadIdx.x;
  if (idx < E_) {
    int srcv = edges[idx];
    int tgtv = edges[E_ + idx];
    int old = atomicExch(&head[srcv * NCHAIN + (idx & (NCHAIN - 1))], idx);
    rec[idx] = make_int2(old, tgtv);
  }
}

// ================= gemmk: 32x64 tiles, BK=128, LDS-staged (round-14 body) =================
__global__ __launch_bounds__(256) void gemmk(const float* __restrict__ x,
                                             const float* __restrict__ W,
                                             const float* __restrict__ bias,
                                             const float* __restrict__ a,
                                             unsigned short* __restrict__ hb,
                                             float* __restrict__ s1p,
                                             float* __restrict__ s2p,
                                             float* __restrict__ hsump,
                                             int N_, int m32) {
  __shared__ unsigned short lA[32][136];  // pad 136: row stride 272B -> 2-way alias (free)
  __shared__ unsigned short lB[64][136];
  __shared__ float s1t[32], s2t[32], ht[64];

  const int tid = threadIdx.x;
  const int vb = blockIdx.x;
  const int mt = vb % m32;
  const int bn4 = vb / m32;              // 0..3
  const int bm = mt * 32;
  const int bn = bn4 * 64;
  const int wave = tid >> 6, lane = tid & 63;
  const int lr = lane & 15, lk = lane >> 4;

  f32x4 acc[2] = {};   // fm in {0,1}: rows bm + fm*16 + lk*4 + i, col bn + wave*16 + lr

  for (int k0 = 0; k0 < IN_F; k0 += 128) {
    // A: 32 rows x 128 k (4 float4/thread), fp32 -> bf16
#pragma unroll
    for (int r = 0; r < 4; ++r) {
      int idx = tid + r * 256;
      int row = idx >> 5, c4 = idx & 31;
      int gm = bm + row;
      float4 va = (gm < N_) ? *(const float4*)&x[(size_t)gm * IN_F + k0 + c4 * 4]
                            : make_float4(0.f, 0.f, 0.f, 0.f);
      ushort4 oa;
      oa.x = f2bf(va.x); oa.y = f2bf(va.y); oa.z = f2bf(va.z); oa.w = f2bf(va.w);
      *(ushort4*)&lA[row][c4 * 4] = oa;
    }
    // B: 64 n-rows x 128 k (8 float4/thread); W is L2-resident (0.5 MB)
#pragma unroll
    for (int r = 0; r < 8; ++r) {
      int idx = tid + r * 256;
      int row = idx >> 5, c4 = idx & 31;
      float4 vb4 = *(const float4*)&W[(size_t)(bn + row) * IN_F + k0 + c4 * 4];
      ushort4 ob;
      ob.x = f2bf(vb4.x); ob.y = f2bf(vb4.y); ob.z = f2bf(vb4.z); ob.w = f2bf(vb4.w);
      *(ushort4*)&lB[row][c4 * 4] = ob;
    }
    __syncthreads();
#pragma unroll
    for (int kk = 0; kk < 128; kk += 32) {
      bf16x8 af[2], bfr;
#pragma unroll
      for (int fm = 0; fm < 2; ++fm)
        af[fm] = *(const bf16x8*)&lA[fm * 16 + lr][kk + lk * 8];
      bfr = *(const bf16x8*)&lB[wave * 16 + lr][kk + lk * 8];
#pragma unroll
      for (int fm = 0; fm < 2; ++fm)
        acc[fm] = __builtin_amdgcn_mfma_f32_16x16x32_bf16(af[fm], bfr, acc[fm], 0, 0, 0);
    }
    __syncthreads();
  }

  // ---- epilogue. C/D layout: col=lane&15, row=(lane>>4)*4+reg ----
  if (tid < 32) { s1t[tid] = 0.f; s2t[tid] = 0.f; }
  __syncthreads();

  const int gcv = bn + wave * 16 + lr;
  const float av = a[gcv], bv2 = a[OUT_F + gcv], biasv = bias[gcv];
  float csum = 0.f;
#pragma unroll
  for (int fm = 0; fm < 2; ++fm) {
#pragma unroll
    for (int i = 0; i < 4; ++i) {
      int lrow = fm * 16 + lk * 4 + i;
      int gr = bm + lrow;
      bool valid = (gr < N_);
      float v = valid ? acc[fm][i] + biasv : 0.f;
      if (valid) hb[(size_t)gr * OUT_F + gcv] = f2bf(v);
      csum += v;
      // partial dot over this wave's 16 cols; combine across the lr group
      float p1 = v * av;
      float p2 = v * bv2;
#pragma unroll
      for (int off = 1; off < 16; off <<= 1) {
        p1 += __shfl_xor(p1, off);
        p2 += __shfl_xor(p2, off);
      }
      if (lr == 0 && valid) {      // 4 waves contribute per row -> LDS combine
        atomicAdd(&s1t[lrow], p1);
        atomicAdd(&s2t[lrow], p2);
      }
    }
  }
  // column sums: rows live across the lk group (xor 16,32); one writer per col
#pragma unroll
  for (int off = 16; off < 64; off <<= 1) csum += __shfl_xor(csum, off);
  if (lk == 0) ht[wave * 16 + lr] = csum;
  __syncthreads();

  if (tid < 32) {
    int gr = bm + tid;
    if (gr < N_) {
      s1p[(size_t)gr * 4 + bn4] = s1t[tid];
      s2p[(size_t)gr * 4 + bn4] = s2t[tid];
    }
  }
  if (tid < 64) hsump[(size_t)mt * OUT_F + bn + tid] = ht[tid];
}

// ================= rowk: 1 row / 128-thread block; uint4 (16B) gather =================
__global__ __launch_bounds__(128) void rowk(const unsigned short* __restrict__ hb,
                                            const float* __restrict__ s1p,
                                            const float* __restrict__ s2p,
                                            const float* __restrict__ hsump,
                                            int* __restrict__ head,
                                            const int2* __restrict__ rec,
                                            float* __restrict__ out,
                                            int N_, int E_, int m32) {
  __shared__ int s_tgt[CAP];
  __shared__ float s_w[CAP];
  __shared__ float s_acc[4][OUT_F];   // per-group gather partials
  __shared__ float s_red[4];
  __shared__ int s_cnt;

  const int t = threadIdx.x;          // 0..127
  const int lane = t & 63, wv = t >> 6;
  const int row = blockIdx.x;
  const float invN = 1.0f / (float)N_;

  if (t == 0) s_cnt = 0;
  __syncthreads();

  // single-pass chain walk: grab slots via LDS cursor (slot order only permutes
  // FP summation order -> ~1ulp wobble, far under threshold)
  if (t < NCHAIN) {
    int e = head[row * NCHAIN + t];
    int guard = 0;
    while (e >= 0 && e < E_ && guard < CAP) {
      int2 rr = rec[e];
      int slot = atomicAdd(&s_cnt, 1);
      if (slot < CAP) s_tgt[slot] = rr.y;
      ++guard;
      e = rr.x;
    }
    // REQUIRED leave-clean reset (round-13 tripwire): next call's edge fill must
    // see negative heads, else stale indices get linked into new chains as cycles.
    head[row * NCHAIN + t] = -1;
  }
  __syncthreads();
  int deg = s_cnt;
  if (deg > CAP) deg = CAP;

  // raw leaky scores; s1/s2 = sum of 4 per-n-block partials (one float4 each)
  float4 sv = *(const float4*)&s1p[(size_t)row * 4];
  float s1i = (sv.x + sv.y) + (sv.z + sv.w);
  for (int q = t; q < deg; q += 128) {
    int tg = s_tgt[q];
    float4 s2v = *(const float4*)&s2p[(size_t)tg * 4];
    float s = s1i + ((s2v.x + s2v.y) + (s2v.z + s2v.w));
    s_w[q] = (s > 0.f) ? s : ALPHA * s;
  }
  __syncthreads();

  // duplicate merge: leader slot gets cnt*score, others -inf (own-slot writes only)
  for (int q = t; q < deg; q += 128) {
    int tg = s_tgt[q];
    int first = q, cnt = 0;
    for (int j = 0; j < deg; ++j) {
      int tj = s_tgt[j];
      cnt += (tj == tg);
      if (tj == tg && j < first) first = j;
    }
    float v;
    if (first == q) {
      v = (float)cnt * s_w[q];
      if (v == 0.f) v = -INFINITY;  // adj==0 -> NEG_BIG -> excluded
    } else {
      v = -INFINITY;
    }
    s_w[q] = v;
  }

  // block max (2 waves)
  float m = -INFINITY;
  for (int q = t; q < deg; q += 128) m = fmaxf(m, s_w[q]);
#pragma unroll
  for (int off = 32; off; off >>= 1) m = fmaxf(m, __shfl_xor(m, off));
  if (lane == 0) s_red[wv] = m;
  __syncthreads();
  m = fmaxf(s_red[0], s_red[1]);

  bool uniform = (deg == 0) || (m == -INFINITY);

  // exp + denom (skipped when uniform -> avoids -inf - -inf NaN)
  float dsum = 0.f;
  if (!uniform) {
    for (int q = t; q < deg; q += 128) {
      float e = __expf(s_w[q] - m);
      s_w[q] = e;
      dsum += e;
    }
  }
#pragma unroll
  for (int off = 32; off; off >>= 1) dsum += __shfl_xor(dsum, off);
  if (lane == 0) s_red[2 + wv] = dsum;
  __syncthreads();
  float inv = 1.0f / (s_red[2] + s_red[3]);

  float2* out2 = (float2*)(out + (size_t)row * OUT_F);
  if (uniform) {
    // empty row -> softmax of constant row -> mean of h (on-demand column sum)
    float A = 0.f, B = 0.f;
    for (int mt = 0; mt < m32; ++mt) {
      A += hsump[(size_t)mt * OUT_F + 2 * t];
      B += hsump[(size_t)mt * OUT_F + 2 * t + 1];
    }
    out2[t] = make_float2(A * invN, B * invN);
    return;
  }

  // ---- gather: 4 groups x 32 lanes; group g handles edges q ≡ g (mod 4).
  // Each lane loads uint4 = 8 bf16 features at lane32*8 (16B, coalesced 512B/edge).
  const int g = t >> 5, lane32 = t & 31;
  float a0 = 0.f, a1 = 0.f, a2 = 0.f, a3 = 0.f, a4 = 0.f, a5 = 0.f, a6 = 0.f, a7 = 0.f;
  const uint4* hb4 = (const uint4*)hb;   // 8 bf16 per uint4; row stride = 32 uint4
#pragma unroll 2
  for (int q = g; q < deg; q += 4) {
    float w = s_w[q];
    uint4 u = hb4[(size_t)s_tgt[q] * 32 + lane32];
    a0 += w * bf_lo(u.x); a1 += w * bf_hi(u.x);
    a2 += w * bf_lo(u.y); a3 += w * bf_hi(u.y);
    a4 += w * bf_lo(u.z); a5 += w * bf_hi(u.z);
    a6 += w * bf_lo(u.w); a7 += w * bf_hi(u.w);
  }
  {
    float* dst = &s_acc[g][lane32 * 8];
    dst[0] = a0; dst[1] = a1; dst[2] = a2; dst[3] = a3;
    dst[4] = a4; dst[5] = a5; dst[6] = a6; dst[7] = a7;
  }
  __syncthreads();
  // combine the 4 group-partials; thread t owns features 2t, 2t+1
  float A = ((s_acc[0][2 * t] + s_acc[1][2 * t]) + (s_acc[2][2 * t] + s_acc[3][2 * t]));
  float B = ((s_acc[0][2 * t + 1] + s_acc[1][2 * t + 1]) +
             (s_acc[2][2 * t + 1] + s_acc[3][2 * t + 1]));
  out2[t] = make_float2(A * inv, B * inv);
}

extern "C" void kernel_launch(void* const* d_in, const int* in_sizes, int n_in,
                              void* d_out, int out_size, void* d_ws, size_t ws_size,
                              hipStream_t stream) {
  const float* x = (const float*)d_in[0];
  const float* W = (const float*)d_in[1];
  const float* b = (const float*)d_in[2];
  const float* a = (const float*)d_in[3];
  const int* edges = (const int*)d_in[4];
  float* out = (float*)d_out;

  int N_ = in_sizes[0] / IN_F;   // 10000
  int E_ = in_sizes[4] / 2;      // 320000

  char* ws = (char*)d_ws;
  size_t off = 0;
  auto alloc = [&](size_t bytes) {
    char* q = ws + off;
    off = (off + bytes + 255) & ~(size_t)255;
    return q;
  };
  int m32 = (N_ + 31) / 32;
  unsigned short* hb    = (unsigned short*)alloc((size_t)N_ * OUT_F * sizeof(unsigned short));
  float*          s1p   = (float*)alloc((size_t)N_ * 4 * sizeof(float));
  float*          s2p   = (float*)alloc((size_t)N_ * 4 * sizeof(float));
  float*          hsump = (float*)alloc((size_t)m32 * OUT_F * sizeof(float));
  int*            head  = (int*)alloc((size_t)NCHAIN * N_ * sizeof(int));
  int2*           rec   = (int2*)alloc((size_t)E_ * sizeof(int2));

  int gblocks = m32 * 4;                 // 32x64 tiles covering 256 cols
  int fblocks = (E_ + 255) / 256;

  fillk<<<fblocks, 256, 0, stream>>>(edges, head, rec, E_);
  gemmk<<<gblocks, 256, 0, stream>>>(x, W, b, a, hb, s1p, s2p, hsump, N_, m32);
  rowk<<<N_, 128, 0, stream>>>(hb, s1p, s2p, hsump, head, rec, out, N_, E_, m32);
}

// Round 17
// 60.128 us; speedup vs baseline: 1.9221x; 1.1607x over previous
//
#include <hip/hip_runtime.h>
#include <hip/hip_bf16.h>
#include <math.h>

#define IN_F 512
#define OUT_F 256
#define ALPHA 0.2f
#define CAP 512     // max row degree; deg ~ Poisson(32)
#define NCHAIN 16   // sub-chains per row for parallel linked-list traversal

typedef __attribute__((ext_vector_type(8))) short bf16x8;
typedef __attribute__((ext_vector_type(4))) float f32x4;

// round-to-nearest (ties up): 2 VALU ops
static __device__ __forceinline__ unsigned short f2bf(float f) {
  unsigned int u = __builtin_bit_cast(unsigned int, f);
  return (unsigned short)((u + 0x8000u) >> 16);
}
static __device__ __forceinline__ float bf_lo(unsigned int u) {
  return __builtin_bit_cast(float, u << 16);
}
static __device__ __forceinline__ float bf_hi(unsigned int u) {
  return __builtin_bit_cast(float, u & 0xffff0000u);
}

// ================= mega: [0,gblocks) = 32x64 GEMM tiles (BK=128), rest = edge fill =================
// Round-16 lesson: splitting fill from gemm costs +7us/dispatch-node, no interference
// existed -> merged 2-dispatch structure is optimal. New: XCD-aware tile mapping —
// the 4 bn4-copies of each m-tile are placed on ONE XCD (vb%8 round-robin assumption)
// so x rows are fetched into a single L2 once (2.5MB/XCD share) instead of via L3 4x.
__global__ __launch_bounds__(256) void mega(const float* __restrict__ x,
                                            const float* __restrict__ W,
                                            const float* __restrict__ bias,
                                            const float* __restrict__ a,
                                            const int* __restrict__ edges,
                                            unsigned short* __restrict__ hb,
                                            float* __restrict__ s1p,
                                            float* __restrict__ s2p,
                                            float* __restrict__ hsump,
                                            int* __restrict__ head,
                                            int2* __restrict__ rec,
                                            int N_, int E_, int m32, int gblocks) {
  const int tid = threadIdx.x;
  const int vb = blockIdx.x;

  if (vb >= gblocks) {
    // ---- edge fill: 16-way per-row linked lists. Heads are negative on entry (0xAA
    // poison call 1; rowk leaves -1 every call — REQUIRED, round-13 tripwire).
    int idx = (vb - gblocks) * 256 + tid;
    if (idx < E_) {
      int srcv = edges[idx];
      int tgtv = edges[E_ + idx];
      int old = atomicExch(&head[srcv * NCHAIN + (idx & (NCHAIN - 1))], idx);
      rec[idx] = make_int2(old, tgtv);
    }
    return;
  }

  // XCD-aware decode: vb = c + 8*(4*mtl + bn4) -> all 4 bn4 of tile mt on XCD c.
  const int c = vb & 7;
  const int s = vb >> 3;
  const int bn4 = s & 3;
  const int mt = (s >> 2) * 8 + c;
  if (mt >= m32) return;                 // padding blocks (gblocks rounded up)

  // ---- GEMM tile 32(m) x 64(n), BK=128; 4 waves, wave = 16-col slice ----
  __shared__ unsigned short lA[32][136];  // pad 136: row stride 272B -> 2-way alias (free)
  __shared__ unsigned short lB[64][136];
  __shared__ float s1t[32], s2t[32], ht[64];

  const int bm = mt * 32;
  const int bn = bn4 * 64;
  const int wave = tid >> 6, lane = tid & 63;
  const int lr = lane & 15, lk = lane >> 4;

  f32x4 acc[2] = {};   // fm in {0,1}: rows bm + fm*16 + lk*4 + i, col bn + wave*16 + lr

  for (int k0 = 0; k0 < IN_F; k0 += 128) {
    // A: 32 rows x 128 k (4 float4/thread), fp32 -> bf16
#pragma unroll
    for (int r = 0; r < 4; ++r) {
      int idx = tid + r * 256;
      int row = idx >> 5, c4 = idx & 31;
      int gm = bm + row;
      float4 va = (gm < N_) ? *(const float4*)&x[(size_t)gm * IN_F + k0 + c4 * 4]
                            : make_float4(0.f, 0.f, 0.f, 0.f);
      ushort4 oa;
      oa.x = f2bf(va.x); oa.y = f2bf(va.y); oa.z = f2bf(va.z); oa.w = f2bf(va.w);
      *(ushort4*)&lA[row][c4 * 4] = oa;
    }
    // B: 64 n-rows x 128 k (8 float4/thread); W is L2-resident (0.5 MB)
#pragma unroll
    for (int r = 0; r < 8; ++r) {
      int idx = tid + r * 256;
      int row = idx >> 5, c4 = idx & 31;
      float4 vb4 = *(const float4*)&W[(size_t)(bn + row) * IN_F + k0 + c4 * 4];
      ushort4 ob;
      ob.x = f2bf(vb4.x); ob.y = f2bf(vb4.y); ob.z = f2bf(vb4.z); ob.w = f2bf(vb4.w);
      *(ushort4*)&lB[row][c4 * 4] = ob;
    }
    __syncthreads();
#pragma unroll
    for (int kk = 0; kk < 128; kk += 32) {
      bf16x8 af[2], bfr;
#pragma unroll
      for (int fm = 0; fm < 2; ++fm)
        af[fm] = *(const bf16x8*)&lA[fm * 16 + lr][kk + lk * 8];
      bfr = *(const bf16x8*)&lB[wave * 16 + lr][kk + lk * 8];
#pragma unroll
      for (int fm = 0; fm < 2; ++fm)
        acc[fm] = __builtin_amdgcn_mfma_f32_16x16x32_bf16(af[fm], bfr, acc[fm], 0, 0, 0);
    }
    __syncthreads();
  }

  // ---- epilogue. C/D layout: col=lane&15, row=(lane>>4)*4+reg ----
  if (tid < 32) { s1t[tid] = 0.f; s2t[tid] = 0.f; }
  __syncthreads();

  const int gcv = bn + wave * 16 + lr;
  const float av = a[gcv], bv2 = a[OUT_F + gcv], biasv = bias[gcv];
  float csum = 0.f;
#pragma unroll
  for (int fm = 0; fm < 2; ++fm) {
#pragma unroll
    for (int i = 0; i < 4; ++i) {
      int lrow = fm * 16 + lk * 4 + i;
      int gr = bm + lrow;
      bool valid = (gr < N_);
      float v = valid ? acc[fm][i] + biasv : 0.f;
      if (valid) hb[(size_t)gr * OUT_F + gcv] = f2bf(v);
      csum += v;
      // partial dot over this wave's 16 cols; combine across the lr group
      float p1 = v * av;
      float p2 = v * bv2;
#pragma unroll
      for (int off = 1; off < 16; off <<= 1) {
        p1 += __shfl_xor(p1, off);
        p2 += __shfl_xor(p2, off);
      }
      if (lr == 0 && valid) {      // 4 waves contribute per row -> LDS combine
        atomicAdd(&s1t[lrow], p1);
        atomicAdd(&s2t[lrow], p2);
      }
    }
  }
  // column sums: rows live across the lk group (xor 16,32); one writer per col
#pragma unroll
  for (int off = 16; off < 64; off <<= 1) csum += __shfl_xor(csum, off);
  if (lk == 0) ht[wave * 16 + lr] = csum;
  __syncthreads();

  if (tid < 32) {
    int gr = bm + tid;
    if (gr < N_) {
      s1p[(size_t)gr * 4 + bn4] = s1t[tid];
      s2p[(size_t)gr * 4 + bn4] = s2t[tid];
    }
  }
  if (tid < 64) hsump[(size_t)mt * OUT_F + bn + tid] = ht[tid];
}

// ================= rowk: 1 row / 128-thread block; uint4 (16B) gather =================
__global__ __launch_bounds__(128) void rowk(const unsigned short* __restrict__ hb,
                                            const float* __restrict__ s1p,
                                            const float* __restrict__ s2p,
                                            const float* __restrict__ hsump,
                                            int* __restrict__ head,
                                            const int2* __restrict__ rec,
                                            float* __restrict__ out,
                                            int N_, int E_, int m32) {
  __shared__ int s_tgt[CAP];
  __shared__ float s_w[CAP];
  __shared__ float s_acc[4][OUT_F];   // per-group gather partials
  __shared__ float s_red[4];
  __shared__ int s_cnt;

  const int t = threadIdx.x;          // 0..127
  const int lane = t & 63, wv = t >> 6;
  const int row = blockIdx.x;
  const float invN = 1.0f / (float)N_;

  if (t == 0) s_cnt = 0;
  __syncthreads();

  // single-pass chain walk: grab slots via LDS cursor (slot order only permutes
  // FP summation order -> ~1ulp wobble, far under threshold)
  if (t < NCHAIN) {
    int e = head[row * NCHAIN + t];
    int guard = 0;
    while (e >= 0 && e < E_ && guard < CAP) {
      int2 rr = rec[e];
      int slot = atomicAdd(&s_cnt, 1);
      if (slot < CAP) s_tgt[slot] = rr.y;
      ++guard;
      e = rr.x;
    }
    // REQUIRED leave-clean reset (round-13 tripwire): next call's edge fill must
    // see negative heads, else stale indices get linked into new chains as cycles.
    head[row * NCHAIN + t] = -1;
  }
  __syncthreads();
  int deg = s_cnt;
  if (deg > CAP) deg = CAP;

  // raw leaky scores; s1/s2 = sum of 4 per-n-block partials (one float4 each)
  float4 sv = *(const float4*)&s1p[(size_t)row * 4];
  float s1i = (sv.x + sv.y) + (sv.z + sv.w);
  for (int q = t; q < deg; q += 128) {
    int tg = s_tgt[q];
    float4 s2v = *(const float4*)&s2p[(size_t)tg * 4];
    float s = s1i + ((s2v.x + s2v.y) + (s2v.z + s2v.w));
    s_w[q] = (s > 0.f) ? s : ALPHA * s;
  }
  __syncthreads();

  // duplicate merge: leader slot gets cnt*score, others -inf (own-slot writes only)
  for (int q = t; q < deg; q += 128) {
    int tg = s_tgt[q];
    int first = q, cnt = 0;
    for (int j = 0; j < deg; ++j) {
      int tj = s_tgt[j];
      cnt += (tj == tg);
      if (tj == tg && j < first) first = j;
    }
    float v;
    if (first == q) {
      v = (float)cnt * s_w[q];
      if (v == 0.f) v = -INFINITY;  // adj==0 -> NEG_BIG -> excluded
    } else {
      v = -INFINITY;
    }
    s_w[q] = v;
  }

  // block max (2 waves)
  float m = -INFINITY;
  for (int q = t; q < deg; q += 128) m = fmaxf(m, s_w[q]);
#pragma unroll
  for (int off = 32; off; off >>= 1) m = fmaxf(m, __shfl_xor(m, off));
  if (lane == 0) s_red[wv] = m;
  __syncthreads();
  m = fmaxf(s_red[0], s_red[1]);

  bool uniform = (deg == 0) || (m == -INFINITY);

  // exp + denom (skipped when uniform -> avoids -inf - -inf NaN)
  float dsum = 0.f;
  if (!uniform) {
    for (int q = t; q < deg; q += 128) {
      float e = __expf(s_w[q] - m);
      s_w[q] = e;
      dsum += e;
    }
  }
#pragma unroll
  for (int off = 32; off; off >>= 1) dsum += __shfl_xor(dsum, off);
  if (lane == 0) s_red[2 + wv] = dsum;
  __syncthreads();
  float inv = 1.0f / (s_red[2] + s_red[3]);

  float2* out2 = (float2*)(out + (size_t)row * OUT_F);
  if (uniform) {
    // empty row -> softmax of constant row -> mean of h (on-demand column sum)
    float A = 0.f, B = 0.f;
    for (int mt = 0; mt < m32; ++mt) {
      A += hsump[(size_t)mt * OUT_F + 2 * t];
      B += hsump[(size_t)mt * OUT_F + 2 * t + 1];
    }
    out2[t] = make_float2(A * invN, B * invN);
    return;
  }

  // ---- gather: 4 groups x 32 lanes; group g handles edges q ≡ g (mod 4).
  // Each lane loads uint4 = 8 bf16 features at lane32*8 (16B, coalesced 512B/edge).
  const int g = t >> 5, lane32 = t & 31;
  float a0 = 0.f, a1 = 0.f, a2 = 0.f, a3 = 0.f, a4 = 0.f, a5 = 0.f, a6 = 0.f, a7 = 0.f;
  const uint4* hb4 = (const uint4*)hb;   // 8 bf16 per uint4; row stride = 32 uint4
#pragma unroll 2
  for (int q = g; q < deg; q += 4) {
    float w = s_w[q];
    uint4 u = hb4[(size_t)s_tgt[q] * 32 + lane32];
    a0 += w * bf_lo(u.x); a1 += w * bf_hi(u.x);
    a2 += w * bf_lo(u.y); a3 += w * bf_hi(u.y);
    a4 += w * bf_lo(u.z); a5 += w * bf_hi(u.z);
    a6 += w * bf_lo(u.w); a7 += w * bf_hi(u.w);
  }
  {
    float* dst = &s_acc[g][lane32 * 8];
    dst[0] = a0; dst[1] = a1; dst[2] = a2; dst[3] = a3;
    dst[4] = a4; dst[5] = a5; dst[6] = a6; dst[7] = a7;
  }
  __syncthreads();
  // combine the 4 group-partials; thread t owns features 2t, 2t+1
  float A = ((s_acc[0][2 * t] + s_acc[1][2 * t]) + (s_acc[2][2 * t] + s_acc[3][2 * t]));
  float B = ((s_acc[0][2 * t + 1] + s_acc[1][2 * t + 1]) +
             (s_acc[2][2 * t + 1] + s_acc[3][2 * t + 1]));
  out2[t] = make_float2(A * inv, B * inv);
}

extern "C" void kernel_launch(void* const* d_in, const int* in_sizes, int n_in,
                              void* d_out, int out_size, void* d_ws, size_t ws_size,
                              hipStream_t stream) {
  const float* x = (const float*)d_in[0];
  const float* W = (const float*)d_in[1];
  const float* b = (const float*)d_in[2];
  const float* a = (const float*)d_in[3];
  const int* edges = (const int*)d_in[4];
  float* out = (float*)d_out;

  int N_ = in_sizes[0] / IN_F;   // 10000
  int E_ = in_sizes[4] / 2;      // 320000

  char* ws = (char*)d_ws;
  size_t off = 0;
  auto alloc = [&](size_t bytes) {
    char* q = ws + off;
    off = (off + bytes + 255) & ~(size_t)255;
    return q;
  };
  int m32 = (N_ + 31) / 32;
  unsigned short* hb    = (unsigned short*)alloc((size_t)N_ * OUT_F * sizeof(unsigned short));
  float*          s1p   = (float*)alloc((size_t)N_ * 4 * sizeof(float));
  float*          s2p   = (float*)alloc((size_t)N_ * 4 * sizeof(float));
  float*          hsump = (float*)alloc((size_t)m32 * OUT_F * sizeof(float));
  int*            head  = (int*)alloc((size_t)NCHAIN * N_ * sizeof(int));
  int2*           rec   = (int2*)alloc((size_t)E_ * sizeof(int2));

  // gblocks padded to 8 XCDs x 4 bn4 x ceil(m32/8) for the bijective XCD swizzle
  int gblocks = ((m32 + 7) / 8) * 8 * 4;
  int fblocks = (E_ + 255) / 256;

  mega<<<gblocks + fblocks, 256, 0, stream>>>(x, W, b, a, edges, hb, s1p, s2p, hsump,
                                              head, rec, N_, E_, m32, gblocks);
  rowk<<<N_, 128, 0, stream>>>(hb, s1p, s2p, hsump, head, rec, out, N_, E_, m32);
}